// Round 2
// baseline (583.669 us; speedup 1.0000x reference)
//
#include <hip/hip_runtime.h>
#include <hip/hip_bf16.h>
#include <math.h>

#define B_ 8
#define S_ 512
#define E_ 768
#define H_ 12
#define HE_ (H_ * E_)

typedef __attribute__((ext_vector_type(8))) short bf16x8;
typedef __attribute__((ext_vector_type(4))) float f32x4;

__device__ inline void gload_lds16(const void* g, void* l) {
  __builtin_amdgcn_global_load_lds(
      (const __attribute__((address_space(1))) unsigned int*)g,
      (__attribute__((address_space(3))) unsigned int*)l, 16, 0, 0);
}

__device__ inline float tof(float v) { return v; }
__device__ inline float tof(__hip_bfloat16 v) { return __bfloat162float(v); }

// ---------- f32 -> bf16 convert ----------
__global__ __launch_bounds__(256) void cvt_kernel(const float* __restrict__ in,
                                                  __hip_bfloat16* __restrict__ out, int n) {
  int i = blockIdx.x * 256 + threadIdx.x;
  if (i < n) out[i] = __float2bfloat16(in[i]);
}

// ---------- transpose [R][C] -> bf16 [C][R], batched over z ----------
template <typename T>
__global__ __launch_bounds__(256) void transpose_kernel(const T* __restrict__ in, long inz,
                                                        __hip_bfloat16* __restrict__ out,
                                                        long outz, int R, int C) {
  __shared__ float t[32][33];
  in += (long)blockIdx.z * inz;
  out += (long)blockIdx.z * outz;
  int bc = blockIdx.x * 32, br = blockIdx.y * 32;
  int tx = threadIdx.x, ty = threadIdx.y;  // block (32,8)
#pragma unroll
  for (int i = ty; i < 32; i += 8) t[i][tx] = tof(in[(long)(br + i) * C + (bc + tx)]);
  __syncthreads();
#pragma unroll
  for (int i = ty; i < 32; i += 8)
    out[(long)(bc + i) * R + (br + tx)] = __float2bfloat16(t[tx][i]);
}

// ---------- MFMA GEMM: C[M,N] = A[M,K] * (BT[N,K])^T, bf16 in, fp32 accum ----------
// Batched over blockIdx.z: zb = z / zmod, zh = z % zmod; offsets = zb*s1 + zh*s2.
// Requires M%128==0, N%128==0, K%64==0. 256 threads = 4 waves, each owning 64x64.
template <bool OUT_BF16, bool ADD_BIAS>
__global__ __launch_bounds__(256) void gemm_bt(
    const __hip_bfloat16* __restrict__ A, long As1, long As2, int lda,
    const __hip_bfloat16* __restrict__ BT, long Bs1, long Bs2, int ldb,
    void* __restrict__ Cv, long Cs1, long Cs2, int ldc,
    const float* __restrict__ bias, long biasS2, int zmod, int K, float scale) {
  constexpr int BM = 128, BN = 128, BK = 64;
  __shared__ __align__(16) __hip_bfloat16 sA[BM * BK];
  __shared__ __align__(16) __hip_bfloat16 sB[BN * BK];
  const int tid = threadIdx.x;
  const int wave = tid >> 6, lane = tid & 63;
  const int r16 = lane & 15, g = lane >> 4;  // fragment row/col within 16, k-group
  const int zb = blockIdx.z / zmod, zh = blockIdx.z % zmod;
  A += (long)zb * As1 + (long)zh * As2;
  BT += (long)zb * Bs1 + (long)zh * Bs2;
  const int bm = blockIdx.y * BM, bn = blockIdx.x * BN;
  const int wm = (wave >> 1) * 64, wn = (wave & 1) * 64;
  f32x4 acc[4][4] = {};
  const int e0 = tid * 8;  // staging: 8 bf16 (16B) per thread per pass

  for (int k0 = 0; k0 < K; k0 += BK) {
#pragma unroll
    for (int p = 0; p < 4; ++p) {  // 4 passes x 256 thr x 8 elems = 128x64 tile
      int ee = p * 2048 + e0;
      int row = ee >> 6, col = ee & 63;
      gload_lds16(A + (long)(bm + row) * lda + (k0 + col), (char*)sA + ee * 2);
      gload_lds16(BT + (long)(bn + row) * ldb + (k0 + col), (char*)sB + ee * 2);
    }
    __syncthreads();  // drains vmcnt for global_load_lds
#pragma unroll
    for (int kk = 0; kk < BK; kk += 32) {
      bf16x8 af[4], bfr[4];
#pragma unroll
      for (int i = 0; i < 4; ++i)
        af[i] = *(const bf16x8*)(const void*)(sA + (wm + i * 16 + r16) * BK + kk + g * 8);
#pragma unroll
      for (int j = 0; j < 4; ++j)
        bfr[j] = *(const bf16x8*)(const void*)(sB + (wn + j * 16 + r16) * BK + kk + g * 8);
#pragma unroll
      for (int i = 0; i < 4; ++i)
#pragma unroll
        for (int j = 0; j < 4; ++j)
          acc[i][j] = __builtin_amdgcn_mfma_f32_16x16x32_bf16(af[i], bfr[j], acc[i][j], 0, 0, 0);
    }
    __syncthreads();
  }

  float* Cf = (float*)Cv;
  __hip_bfloat16* Cb = (__hip_bfloat16*)Cv;
  const long cbase = (long)zb * Cs1 + (long)zh * Cs2;
#pragma unroll
  for (int i = 0; i < 4; ++i) {
    int row0 = bm + wm + i * 16 + g * 4;
#pragma unroll
    for (int j = 0; j < 4; ++j) {
      int col = bn + wn + j * 16 + r16;
      float bv = ADD_BIAS ? bias[(long)zh * biasS2 + col] : 0.0f;
#pragma unroll
      for (int r = 0; r < 4; ++r) {
        float v = acc[i][j][r] * scale + bv;
        long off = cbase + (long)(row0 + r) * ldc + col;
        if (OUT_BF16)
          Cb[off] = __float2bfloat16(v);
        else
          Cf[off] = v;
      }
    }
  }
}

// ---------- masked softmax over rows of 512, bf16 in -> bf16 out, IN-PLACE ----------
// Each block owns one row exclusively; full row loaded before first barrier,
// stores only after, so in-place is race-free.
__global__ __launch_bounds__(256) void softmax_kernel(__hip_bfloat16* __restrict__ scores,
                                                      const int* __restrict__ mask) {
  const int q = blockIdx.x, h = blockIdx.y, b = blockIdx.z;
  const int tid = threadIdx.x;
  const long base = (((long)b * H_ + h) * S_ + q) * S_;
  const int* mrow = mask + (long)b * S_;
  float v0 = __bfloat162float(scores[base + tid]);
  float v1 = __bfloat162float(scores[base + 256 + tid]);
  if (mrow[tid] == 1) v0 = -INFINITY;
  if (mrow[256 + tid] == 1) v1 = -INFINITY;
  float m = fmaxf(v0, v1);
#pragma unroll
  for (int o = 32; o; o >>= 1) m = fmaxf(m, __shfl_xor(m, o));
  __shared__ float red[8];
  const int wave = tid >> 6, lane = tid & 63;
  if (lane == 0) red[wave] = m;
  __syncthreads();
  m = fmaxf(fmaxf(red[0], red[1]), fmaxf(red[2], red[3]));
  float e0 = expf(v0 - m), e1 = expf(v1 - m);
  float s = e0 + e1;
#pragma unroll
  for (int o = 32; o; o >>= 1) s += __shfl_xor(s, o);
  if (lane == 0) red[4 + wave] = s;
  __syncthreads();
  s = red[4] + red[5] + red[6] + red[7];
  float inv = 1.0f / s;
  scores[base + tid] = __float2bfloat16(e0 * inv);
  scores[base + 256 + tid] = __float2bfloat16(e1 * inv);
}

// ---------- LayerNorm over E=768, one block per row ----------
__global__ __launch_bounds__(256) void ln_kernel(const float* __restrict__ y,
                                                 const float* __restrict__ gamma,
                                                 const float* __restrict__ beta,
                                                 float* __restrict__ out) {
  const long base = (long)blockIdx.x * E_;
  const int tid = threadIdx.x;
  float a = y[base + tid], b = y[base + 256 + tid], c = y[base + 512 + tid];
  float s = a + b + c;
  float ss = a * a + b * b + c * c;
#pragma unroll
  for (int o = 32; o; o >>= 1) {
    s += __shfl_xor(s, o);
    ss += __shfl_xor(ss, o);
  }
  __shared__ float r1[4], r2[4];
  const int wave = tid >> 6, lane = tid & 63;
  if (lane == 0) { r1[wave] = s; r2[wave] = ss; }
  __syncthreads();
  s = r1[0] + r1[1] + r1[2] + r1[3];
  ss = r2[0] + r2[1] + r2[2] + r2[3];
  const float mu = s * (1.0f / E_);
  const float var = ss * (1.0f / E_) - mu * mu;
  const float rstd = rsqrtf(var + 1e-5f);
  out[base + tid] = (a - mu) * rstd * gamma[tid] + beta[tid];
  out[base + 256 + tid] = (b - mu) * rstd * gamma[256 + tid] + beta[256 + tid];
  out[base + 512 + tid] = (c - mu) * rstd * gamma[512 + tid] + beta[512 + tid];
}

extern "C" void kernel_launch(void* const* d_in, const int* in_sizes, int n_in,
                              void* d_out, int out_size, void* d_ws, size_t ws_size,
                              hipStream_t stream) {
  const float* x = (const float*)d_in[0];
  const int* mask = (const int*)d_in[1];
  const float* Wh = (const float*)d_in[2];
  const float* bh = (const float*)d_in[3];
  const float* Wo = (const float*)d_in[4];
  const float* bo = (const float*)d_in[5];
  const float* gamma = (const float*)d_in[6];
  const float* beta = (const float*)d_in[7];
  float* out = (float*)d_out;

  // ---- workspace: phase-aliased regions, total ~215.5 MB ----
  const size_t nX = (size_t)B_ * S_ * E_;        // 3,145,728
  const size_t nWh = (size_t)H_ * E_ * E_;       // 7,077,888
  const size_t nP = (size_t)B_ * H_ * S_ * E_;   // 37,748,736
  const size_t nSc = (size_t)B_ * H_ * S_ * S_;  // 25,165,824
  char* base = (char*)d_ws;
  // R_A: p, later cat (p dead after GEMM2/transpose; GEMM3 reads attn+pT only)
  __hip_bfloat16* p = (__hip_bfloat16*)base;
  __hip_bfloat16* cat = p;
  char* RB = base + nP * 2;  // 75,497,472 (256-aligned)
  // R_B: pT, later y (pT dead after GEMM3)
  __hip_bfloat16* pT = (__hip_bfloat16*)RB;
  float* y = (float*)RB;
  char* RC = RB + nP * 2;
  // R_C: xb + WhT early (dead after GEMM1), then scores/attn bf16 (in-place softmax)
  __hip_bfloat16* xb = (__hip_bfloat16*)RC;
  __hip_bfloat16* WhT = (__hip_bfloat16*)(RC + nX * 2);
  __hip_bfloat16* scores = (__hip_bfloat16*)RC;
  char* RD = RC + nSc * 2;
  // R_D: WoT (live until GEMM4)
  __hip_bfloat16* WoT = (__hip_bfloat16*)RD;

  dim3 t256(256);
  dim3 tT(32, 8);
  const float inv_sqrtE = 1.0f / sqrtf((float)E_);

  // 1. x -> bf16
  cvt_kernel<<<dim3(nX / 256), t256, 0, stream>>>(x, xb, (int)nX);
  // 2. WhT[h][o][e] = Wh[h][e][o]
  transpose_kernel<float><<<dim3(24, 24, 12), tT, 0, stream>>>(Wh, (long)E_ * E_, WhT,
                                                               (long)E_ * E_, E_, E_);
  // 3. WoT[o][k] = Wo[k][o]  (k over H*E)
  transpose_kernel<float><<<dim3(24, 288, 1), tT, 0, stream>>>(Wo, 0, WoT, 0, HE_, E_);
  // 4. p[b,h,s,o] = x[b,s,:]·Wh[h,:,o] + bh[h,o]   (bf16 out)
  gemm_bt<true, true><<<dim3(6, 4, B_ * H_), t256, 0, stream>>>(
      xb, (long)S_ * E_, 0, E_, WhT, 0, (long)E_ * E_, E_, p, (long)H_ * S_ * E_,
      (long)S_ * E_, E_, bh, E_, H_, E_, 1.0f);
  // 5. pT[b,h,e,s] = p[b,h,s,e]
  transpose_kernel<__hip_bfloat16><<<dim3(24, 16, B_ * H_), tT, 0, stream>>>(
      p, (long)S_ * E_, pT, (long)S_ * E_, S_, E_);
  // 6. scores = (p · p^T) / sqrt(E)   (bf16 out, overwrites dead xb/WhT)
  gemm_bt<true, false><<<dim3(4, 4, B_ * H_), t256, 0, stream>>>(
      p, (long)H_ * S_ * E_, (long)S_ * E_, E_, p, (long)H_ * S_ * E_, (long)S_ * E_, E_,
      scores, (long)H_ * S_ * S_, (long)S_ * S_, S_, nullptr, 0, H_, E_, inv_sqrtE);
  // 7. masked softmax in-place -> attn (bf16)
  softmax_kernel<<<dim3(S_, H_, B_), t256, 0, stream>>>(scores, mask);
  // 8. o = attn · p  written straight into cat[b,s,h*E+e]  (bf16, overwrites dead p)
  gemm_bt<true, false><<<dim3(6, 4, B_ * H_), t256, 0, stream>>>(
      scores, (long)H_ * S_ * S_, (long)S_ * S_, S_, pT, (long)H_ * E_ * S_, (long)E_ * S_,
      S_, cat, (long)S_ * HE_, (long)E_, HE_, nullptr, 0, H_, S_, 1.0f);
  // 9. y = cat · Wo + bo   (fp32, overwrites dead pT)
  gemm_bt<false, true><<<dim3(6, 32, 1), t256, 0, stream>>>(
      cat, 0, 0, HE_, WoT, 0, 0, HE_, y, 0, 0, E_, bo, 0, 1, HE_, 1.0f);
  // 10. LayerNorm -> out
  ln_kernel<<<dim3(B_ * S_), t256, 0, stream>>>(y, gamma, beta, out);
}

// Round 3
// 516.118 us; speedup vs baseline: 1.1309x; 1.1309x over previous
//
#include <hip/hip_runtime.h>
#include <hip/hip_bf16.h>
#include <math.h>

#define B_ 8
#define S_ 512
#define E_ 768
#define H_ 12
#define HE_ (H_ * E_)
#define KSPLIT 6
#define KCHUNK (HE_ / KSPLIT)  // 1536

typedef __attribute__((ext_vector_type(8))) short bf16x8;
typedef __attribute__((ext_vector_type(4))) float f32x4;

__device__ inline void gload_lds16(const void* g, void* l) {
  __builtin_amdgcn_global_load_lds(
      (const __attribute__((address_space(1))) unsigned int*)g,
      (__attribute__((address_space(3))) unsigned int*)l, 16, 0, 0);
}

__device__ inline float tof(float v) { return v; }
__device__ inline float tof(__hip_bfloat16 v) { return __bfloat162float(v); }

// ---------- f32 -> bf16 convert ----------
__global__ __launch_bounds__(256) void cvt_kernel(const float* __restrict__ in,
                                                  __hip_bfloat16* __restrict__ out, int n) {
  int i = blockIdx.x * 256 + threadIdx.x;
  if (i < n) out[i] = __float2bfloat16(in[i]);
}

// ---------- transpose [R][C] -> bf16 [C][R], batched over z ----------
template <typename T>
__global__ __launch_bounds__(256) void transpose_kernel(const T* __restrict__ in, long inz,
                                                        __hip_bfloat16* __restrict__ out,
                                                        long outz, int R, int C) {
  __shared__ float t[32][33];
  in += (long)blockIdx.z * inz;
  out += (long)blockIdx.z * outz;
  int bc = blockIdx.x * 32, br = blockIdx.y * 32;
  int tx = threadIdx.x, ty = threadIdx.y;  // block (32,8)
#pragma unroll
  for (int i = ty; i < 32; i += 8) t[i][tx] = tof(in[(long)(br + i) * C + (bc + tx)]);
  __syncthreads();
#pragma unroll
  for (int i = ty; i < 32; i += 8)
    out[(long)(bc + i) * R + (br + tx)] = __float2bfloat16(t[tx][i]);
}

// ---------- MFMA GEMM: C[M,N] = A[M,K] * (BT[N,K])^T, bf16 in, fp32 accum ----------
// Batched over blockIdx.z: zb = z / zmod, zh = z % zmod; offsets = zb*s1 + zh*s2.
// Requires M%128==0, N%128==0, K%64==0. 256 threads = 4 waves, each owning 64x64.
template <bool OUT_BF16, bool ADD_BIAS>
__global__ __launch_bounds__(256) void gemm_bt(
    const __hip_bfloat16* __restrict__ A, long As1, long As2, int lda,
    const __hip_bfloat16* __restrict__ BT, long Bs1, long Bs2, int ldb,
    void* __restrict__ Cv, long Cs1, long Cs2, int ldc,
    const float* __restrict__ bias, long biasS2, int zmod, int K, float scale) {
  constexpr int BM = 128, BN = 128, BK = 64;
  __shared__ __align__(16) __hip_bfloat16 sA[BM * BK];
  __shared__ __align__(16) __hip_bfloat16 sB[BN * BK];
  const int tid = threadIdx.x;
  const int wave = tid >> 6, lane = tid & 63;
  const int r16 = lane & 15, g = lane >> 4;  // fragment row/col within 16, k-group
  const int zb = blockIdx.z / zmod, zh = blockIdx.z % zmod;
  A += (long)zb * As1 + (long)zh * As2;
  BT += (long)zb * Bs1 + (long)zh * Bs2;
  const int bm = blockIdx.y * BM, bn = blockIdx.x * BN;
  const int wm = (wave >> 1) * 64, wn = (wave & 1) * 64;
  f32x4 acc[4][4] = {};
  const int e0 = tid * 8;  // staging: 8 bf16 (16B) per thread per pass

  for (int k0 = 0; k0 < K; k0 += BK) {
#pragma unroll
    for (int p = 0; p < 4; ++p) {  // 4 passes x 256 thr x 8 elems = 128x64 tile
      int ee = p * 2048 + e0;
      int row = ee >> 6, col = ee & 63;
      gload_lds16(A + (long)(bm + row) * lda + (k0 + col), (char*)sA + ee * 2);
      gload_lds16(BT + (long)(bn + row) * ldb + (k0 + col), (char*)sB + ee * 2);
    }
    __syncthreads();  // drains vmcnt for global_load_lds
#pragma unroll
    for (int kk = 0; kk < BK; kk += 32) {
      bf16x8 af[4], bfr[4];
#pragma unroll
      for (int i = 0; i < 4; ++i)
        af[i] = *(const bf16x8*)(const void*)(sA + (wm + i * 16 + r16) * BK + kk + g * 8);
#pragma unroll
      for (int j = 0; j < 4; ++j)
        bfr[j] = *(const bf16x8*)(const void*)(sB + (wn + j * 16 + r16) * BK + kk + g * 8);
#pragma unroll
      for (int i = 0; i < 4; ++i)
#pragma unroll
        for (int j = 0; j < 4; ++j)
          acc[i][j] = __builtin_amdgcn_mfma_f32_16x16x32_bf16(af[i], bfr[j], acc[i][j], 0, 0, 0);
    }
    __syncthreads();
  }

  float* Cf = (float*)Cv;
  __hip_bfloat16* Cb = (__hip_bfloat16*)Cv;
  const long cbase = (long)zb * Cs1 + (long)zh * Cs2;
#pragma unroll
  for (int i = 0; i < 4; ++i) {
    int row0 = bm + wm + i * 16 + g * 4;
#pragma unroll
    for (int j = 0; j < 4; ++j) {
      int col = bn + wn + j * 16 + r16;
      float bv = ADD_BIAS ? bias[(long)zh * biasS2 + col] : 0.0f;
#pragma unroll
      for (int r = 0; r < 4; ++r) {
        float v = acc[i][j][r] * scale + bv;
        long off = cbase + (long)(row0 + r) * ldc + col;
        if (OUT_BF16)
          Cb[off] = __float2bfloat16(v);
        else
          Cf[off] = v;
      }
    }
  }
}

// ---------- masked softmax over rows of 512, bf16 in -> bf16 out, IN-PLACE ----------
__global__ __launch_bounds__(256) void softmax_kernel(__hip_bfloat16* __restrict__ scores,
                                                      const int* __restrict__ mask) {
  const int q = blockIdx.x, h = blockIdx.y, b = blockIdx.z;
  const int tid = threadIdx.x;
  const long base = (((long)b * H_ + h) * S_ + q) * S_;
  const int* mrow = mask + (long)b * S_;
  float v0 = __bfloat162float(scores[base + tid]);
  float v1 = __bfloat162float(scores[base + 256 + tid]);
  if (mrow[tid] == 1) v0 = -INFINITY;
  if (mrow[256 + tid] == 1) v1 = -INFINITY;
  float m = fmaxf(v0, v1);
#pragma unroll
  for (int o = 32; o; o >>= 1) m = fmaxf(m, __shfl_xor(m, o));
  __shared__ float red[8];
  const int wave = tid >> 6, lane = tid & 63;
  if (lane == 0) red[wave] = m;
  __syncthreads();
  m = fmaxf(fmaxf(red[0], red[1]), fmaxf(red[2], red[3]));
  float e0 = expf(v0 - m), e1 = expf(v1 - m);
  float s = e0 + e1;
#pragma unroll
  for (int o = 32; o; o >>= 1) s += __shfl_xor(s, o);
  if (lane == 0) red[4 + wave] = s;
  __syncthreads();
  s = red[4] + red[5] + red[6] + red[7];
  float inv = 1.0f / s;
  scores[base + tid] = __float2bfloat16(e0 * inv);
  scores[base + 256 + tid] = __float2bfloat16(e1 * inv);
}

// ---------- reduce KSPLIT partials + bias + LayerNorm over E=768 ----------
__global__ __launch_bounds__(256) void ln_kernel(const float* __restrict__ yp,
                                                 const float* __restrict__ bo,
                                                 const float* __restrict__ gamma,
                                                 const float* __restrict__ beta,
                                                 float* __restrict__ out) {
  const long nY = (long)B_ * S_ * E_;
  const long base = (long)blockIdx.x * E_;
  const int tid = threadIdx.x;
  float a = bo[tid], b = bo[256 + tid], c = bo[512 + tid];
#pragma unroll
  for (int k = 0; k < KSPLIT; ++k) {
    const float* y = yp + k * nY + base;
    a += y[tid];
    b += y[256 + tid];
    c += y[512 + tid];
  }
  float s = a + b + c;
  float ss = a * a + b * b + c * c;
#pragma unroll
  for (int o = 32; o; o >>= 1) {
    s += __shfl_xor(s, o);
    ss += __shfl_xor(ss, o);
  }
  __shared__ float r1[4], r2[4];
  const int wave = tid >> 6, lane = tid & 63;
  if (lane == 0) { r1[wave] = s; r2[wave] = ss; }
  __syncthreads();
  s = r1[0] + r1[1] + r1[2] + r1[3];
  ss = r2[0] + r2[1] + r2[2] + r2[3];
  const float mu = s * (1.0f / E_);
  const float var = ss * (1.0f / E_) - mu * mu;
  const float rstd = rsqrtf(var + 1e-5f);
  out[base + tid] = (a - mu) * rstd * gamma[tid] + beta[tid];
  out[base + 256 + tid] = (b - mu) * rstd * gamma[256 + tid] + beta[256 + tid];
  out[base + 512 + tid] = (c - mu) * rstd * gamma[512 + tid] + beta[512 + tid];
}

extern "C" void kernel_launch(void* const* d_in, const int* in_sizes, int n_in,
                              void* d_out, int out_size, void* d_ws, size_t ws_size,
                              hipStream_t stream) {
  const float* x = (const float*)d_in[0];
  const int* mask = (const int*)d_in[1];
  const float* Wh = (const float*)d_in[2];
  const float* bh = (const float*)d_in[3];
  const float* Wo = (const float*)d_in[4];
  const float* bo = (const float*)d_in[5];
  const float* gamma = (const float*)d_in[6];
  const float* beta = (const float*)d_in[7];
  float* out = (float*)d_out;

  // ---- workspace: phase-aliased regions, total ~215.5 MB ----
  const size_t nX = (size_t)B_ * S_ * E_;        // 3,145,728
  const size_t nP = (size_t)B_ * H_ * S_ * E_;   // 37,748,736
  const size_t nSc = (size_t)B_ * H_ * S_ * S_;  // 25,165,824
  char* base = (char*)d_ws;
  // R_A: p, later cat (p dead after pT transpose + GEMM2)
  __hip_bfloat16* p = (__hip_bfloat16*)base;
  __hip_bfloat16* cat = p;
  char* RB = base + nP * 2;  // 75,497,472 B
  // R_B: pT, later y partials (pT dead after GEMM3); 6 x 12.58MB fp32 = 75.5MB exact
  __hip_bfloat16* pT = (__hip_bfloat16*)RB;
  float* ypart = (float*)RB;
  char* RC = RB + nP * 2;
  // R_C: xb + WhT early (dead after GEMM1), then scores/attn bf16 (in-place softmax)
  __hip_bfloat16* xb = (__hip_bfloat16*)RC;
  __hip_bfloat16* WhT = (__hip_bfloat16*)(RC + nX * 2);
  __hip_bfloat16* scores = (__hip_bfloat16*)RC;
  char* RD = RC + nSc * 2;
  // R_D: WoT (live until GEMM4)
  __hip_bfloat16* WoT = (__hip_bfloat16*)RD;

  dim3 t256(256);
  dim3 tT(32, 8);
  const float inv_sqrtE = 1.0f / sqrtf((float)E_);

  // 1. x -> bf16
  cvt_kernel<<<dim3(nX / 256), t256, 0, stream>>>(x, xb, (int)nX);
  // 2. WhT[h][o][e] = Wh[h][e][o]
  transpose_kernel<float><<<dim3(24, 24, 12), tT, 0, stream>>>(Wh, (long)E_ * E_, WhT,
                                                               (long)E_ * E_, E_, E_);
  // 3. WoT[o][k] = Wo[k][o]  (k over H*E)
  transpose_kernel<float><<<dim3(24, 288, 1), tT, 0, stream>>>(Wo, 0, WoT, 0, HE_, E_);
  // 4. p[b,h,s,o] = x[b,s,:]·Wh[h,:,o] + bh[h,o]   (bf16 out)
  gemm_bt<true, true><<<dim3(6, 4, B_ * H_), t256, 0, stream>>>(
      xb, (long)S_ * E_, 0, E_, WhT, 0, (long)E_ * E_, E_, p, (long)H_ * S_ * E_,
      (long)S_ * E_, E_, bh, E_, H_, E_, 1.0f);
  // 5. pT[b,h,e,s] = p[b,h,s,e]
  transpose_kernel<__hip_bfloat16><<<dim3(24, 16, B_ * H_), tT, 0, stream>>>(
      p, (long)S_ * E_, pT, (long)S_ * E_, S_, E_);
  // 6. scores = (p · p^T) / sqrt(E)   (bf16 out, overwrites dead xb/WhT)
  gemm_bt<true, false><<<dim3(4, 4, B_ * H_), t256, 0, stream>>>(
      p, (long)H_ * S_ * E_, (long)S_ * E_, E_, p, (long)H_ * S_ * E_, (long)S_ * E_, E_,
      scores, (long)H_ * S_ * S_, (long)S_ * S_, S_, nullptr, 0, H_, E_, inv_sqrtE);
  // 7. masked softmax in-place -> attn (bf16)
  softmax_kernel<<<dim3(S_, H_, B_), t256, 0, stream>>>(scores, mask);
  // 8. o = attn · p  written straight into cat[b,s,h*E+e]  (bf16, overwrites dead p)
  gemm_bt<true, false><<<dim3(6, 4, B_ * H_), t256, 0, stream>>>(
      scores, (long)H_ * S_ * S_, (long)S_ * S_, S_, pT, (long)H_ * E_ * S_, (long)E_ * S_,
      S_, cat, (long)S_ * HE_, (long)E_, HE_, nullptr, 0, H_, S_, 1.0f);
  // 9. split-K: ypart[c] = cat[:, c*1536:+1536] · WoT[:, c*1536:+1536]^T  (fp32)
  //    grid (6 n-blocks, 32 m-blocks, 6 k-chunks) = 1152 blocks
  gemm_bt<false, false><<<dim3(6, 32, KSPLIT), t256, 0, stream>>>(
      cat, 0, KCHUNK, HE_, WoT, 0, KCHUNK, HE_, ypart, 0, (long)B_ * S_ * E_, E_,
      nullptr, 0, KSPLIT, KCHUNK, 1.0f);
  // 10. reduce partials + bias + LayerNorm -> out
  ln_kernel<<<dim3(B_ * S_), t256, 0, stream>>>(ypart, bo, gamma, beta, out);
}

// Round 4
// 462.274 us; speedup vs baseline: 1.2626x; 1.1165x over previous
//
#include <hip/hip_runtime.h>
#include <hip/hip_bf16.h>
#include <math.h>

#define B_ 8
#define S_ 512
#define E_ 768
#define H_ 12
#define HE_ (H_ * E_)
#define KSPLIT 6
#define KCHUNK (HE_ / KSPLIT)  // 1536

typedef __attribute__((ext_vector_type(8))) short bf16x8;
typedef __attribute__((ext_vector_type(4))) float f32x4;

__device__ inline void gload_lds16(const void* g, void* l) {
  __builtin_amdgcn_global_load_lds(
      (const __attribute__((address_space(1))) unsigned int*)g,
      (__attribute__((address_space(3))) unsigned int*)l, 16, 0, 0);
}

__device__ inline float tof(float v) { return v; }
__device__ inline float tof(__hip_bfloat16 v) { return __bfloat162float(v); }

// ---------- f32 -> bf16 convert ----------
__global__ __launch_bounds__(256) void cvt_kernel(const float* __restrict__ in,
                                                  __hip_bfloat16* __restrict__ out, int n) {
  int i = blockIdx.x * 256 + threadIdx.x;
  if (i < n) out[i] = __float2bfloat16(in[i]);
}

// ---------- transpose [R][C] -> bf16 [C][R], batched over z ----------
template <typename T>
__global__ __launch_bounds__(256) void transpose_kernel(const T* __restrict__ in, long inz,
                                                        __hip_bfloat16* __restrict__ out,
                                                        long outz, int R, int C) {
  __shared__ float t[32][33];
  in += (long)blockIdx.z * inz;
  out += (long)blockIdx.z * outz;
  int bc = blockIdx.x * 32, br = blockIdx.y * 32;
  int tx = threadIdx.x, ty = threadIdx.y;  // block (32,8)
#pragma unroll
  for (int i = ty; i < 32; i += 8) t[i][tx] = tof(in[(long)(br + i) * C + (bc + tx)]);
  __syncthreads();
#pragma unroll
  for (int i = ty; i < 32; i += 8)
    out[(long)(bc + i) * R + (br + tx)] = __float2bfloat16(t[tx][i]);
}

// ---------- MFMA GEMM: C[M,N] = A[M,K] * (BT[N,K])^T, bf16 in, fp32 accum ----------
// 1D grid with XCD-chunked swizzle (T1): requires gridDim.x % 8 == 0.
// Work id w -> (bx, by, bz) x-fastest; bz: zb = bz / zmod, zh = bz % zmod.
// Requires M%128==0, N%128==0, K%64==0. 256 threads = 4 waves, each owning 64x64.
template <bool OUT_BF16, bool ADD_BIAS>
__global__ __launch_bounds__(256) void gemm_bt(
    const __hip_bfloat16* __restrict__ A, long As1, long As2, int lda,
    const __hip_bfloat16* __restrict__ BT, long Bs1, long Bs2, int ldb,
    void* __restrict__ Cv, long Cs1, long Cs2, int ldc,
    const float* __restrict__ bias, long biasS2, int zmod, int K, float scale,
    int nx, int ny) {
  constexpr int BM = 128, BN = 128, BK = 64;
  __shared__ __align__(16) __hip_bfloat16 sA[BM * BK];
  __shared__ __align__(16) __hip_bfloat16 sB[BN * BK];
  // T1: XCD-chunked bijective remap (nwg % 8 == 0 guaranteed by launches).
  const int nwg = gridDim.x;
  const int cpx = nwg >> 3;
  const int id = blockIdx.x;
  const int w = (id & 7) * cpx + (id >> 3);
  const int bz = w / (nx * ny);
  const int rem = w - bz * nx * ny;
  const int by = rem / nx;
  const int bx = rem - by * nx;

  const int tid = threadIdx.x;
  const int wave = tid >> 6, lane = tid & 63;
  const int r16 = lane & 15, g = lane >> 4;  // fragment row/col within 16, k-group
  const int zb = bz / zmod, zh = bz % zmod;
  A += (long)zb * As1 + (long)zh * As2;
  BT += (long)zb * Bs1 + (long)zh * Bs2;
  const int bm = by * BM, bn = bx * BN;
  const int wm = (wave >> 1) * 64, wn = (wave & 1) * 64;
  f32x4 acc[4][4] = {};
  const int e0 = tid * 8;  // staging: 8 bf16 (16B) per thread per pass

  for (int k0 = 0; k0 < K; k0 += BK) {
#pragma unroll
    for (int p = 0; p < 4; ++p) {  // 4 passes x 256 thr x 8 elems = 128x64 tile
      int ee = p * 2048 + e0;
      int row = ee >> 6, col = ee & 63;
      gload_lds16(A + (long)(bm + row) * lda + (k0 + col), (char*)sA + ee * 2);
      gload_lds16(BT + (long)(bn + row) * ldb + (k0 + col), (char*)sB + ee * 2);
    }
    __syncthreads();  // drains vmcnt for global_load_lds
#pragma unroll
    for (int kk = 0; kk < BK; kk += 32) {
      bf16x8 af[4], bfr[4];
#pragma unroll
      for (int i = 0; i < 4; ++i)
        af[i] = *(const bf16x8*)(const void*)(sA + (wm + i * 16 + r16) * BK + kk + g * 8);
#pragma unroll
      for (int j = 0; j < 4; ++j)
        bfr[j] = *(const bf16x8*)(const void*)(sB + (wn + j * 16 + r16) * BK + kk + g * 8);
#pragma unroll
      for (int i = 0; i < 4; ++i)
#pragma unroll
        for (int j = 0; j < 4; ++j)
          acc[i][j] = __builtin_amdgcn_mfma_f32_16x16x32_bf16(af[i], bfr[j], acc[i][j], 0, 0, 0);
    }
    __syncthreads();
  }

  float* Cf = (float*)Cv;
  __hip_bfloat16* Cb = (__hip_bfloat16*)Cv;
  const long cbase = (long)zb * Cs1 + (long)zh * Cs2;
#pragma unroll
  for (int i = 0; i < 4; ++i) {
    int row0 = bm + wm + i * 16 + g * 4;
#pragma unroll
    for (int j = 0; j < 4; ++j) {
      int col = bn + wn + j * 16 + r16;
      float bv = ADD_BIAS ? bias[(long)zh * biasS2 + col] : 0.0f;
#pragma unroll
      for (int r = 0; r < 4; ++r) {
        float v = acc[i][j][r] * scale + bv;
        long off = cbase + (long)(row0 + r) * ldc + col;
        if (OUT_BF16)
          Cb[off] = __float2bfloat16(v);
        else
          Cf[off] = v;
      }
    }
  }
}

// ---------- masked softmax over rows of 512, bf16 in -> bf16 out, IN-PLACE ----------
__global__ __launch_bounds__(256) void softmax_kernel(__hip_bfloat16* __restrict__ scores,
                                                      const int* __restrict__ mask) {
  const int q = blockIdx.x, h = blockIdx.y, b = blockIdx.z;
  const int tid = threadIdx.x;
  const long base = (((long)b * H_ + h) * S_ + q) * S_;
  const int* mrow = mask + (long)b * S_;
  float v0 = __bfloat162float(scores[base + tid]);
  float v1 = __bfloat162float(scores[base + 256 + tid]);
  if (mrow[tid] == 1) v0 = -INFINITY;
  if (mrow[256 + tid] == 1) v1 = -INFINITY;
  float m = fmaxf(v0, v1);
#pragma unroll
  for (int o = 32; o; o >>= 1) m = fmaxf(m, __shfl_xor(m, o));
  __shared__ float red[8];
  const int wave = tid >> 6, lane = tid & 63;
  if (lane == 0) red[wave] = m;
  __syncthreads();
  m = fmaxf(fmaxf(red[0], red[1]), fmaxf(red[2], red[3]));
  float e0 = expf(v0 - m), e1 = expf(v1 - m);
  float s = e0 + e1;
#pragma unroll
  for (int o = 32; o; o >>= 1) s += __shfl_xor(s, o);
  if (lane == 0) red[4 + wave] = s;
  __syncthreads();
  s = red[4] + red[5] + red[6] + red[7];
  float inv = 1.0f / s;
  scores[base + tid] = __float2bfloat16(e0 * inv);
  scores[base + 256 + tid] = __float2bfloat16(e1 * inv);
}

// ---------- reduce KSPLIT partials + bias + LayerNorm over E=768 ----------
__global__ __launch_bounds__(256) void ln_kernel(const float* __restrict__ yp,
                                                 const float* __restrict__ bo,
                                                 const float* __restrict__ gamma,
                                                 const float* __restrict__ beta,
                                                 float* __restrict__ out) {
  const long nY = (long)B_ * S_ * E_;
  const long base = (long)blockIdx.x * E_;
  const int tid = threadIdx.x;
  float a = bo[tid], b = bo[256 + tid], c = bo[512 + tid];
#pragma unroll
  for (int k = 0; k < KSPLIT; ++k) {
    const float* y = yp + k * nY + base;
    a += y[tid];
    b += y[256 + tid];
    c += y[512 + tid];
  }
  float s = a + b + c;
  float ss = a * a + b * b + c * c;
#pragma unroll
  for (int o = 32; o; o >>= 1) {
    s += __shfl_xor(s, o);
    ss += __shfl_xor(ss, o);
  }
  __shared__ float r1[4], r2[4];
  const int wave = tid >> 6, lane = tid & 63;
  if (lane == 0) { r1[wave] = s; r2[wave] = ss; }
  __syncthreads();
  s = r1[0] + r1[1] + r1[2] + r1[3];
  ss = r2[0] + r2[1] + r2[2] + r2[3];
  const float mu = s * (1.0f / E_);
  const float var = ss * (1.0f / E_) - mu * mu;
  const float rstd = rsqrtf(var + 1e-5f);
  out[base + tid] = (a - mu) * rstd * gamma[tid] + beta[tid];
  out[base + 256 + tid] = (b - mu) * rstd * gamma[256 + tid] + beta[256 + tid];
  out[base + 512 + tid] = (c - mu) * rstd * gamma[512 + tid] + beta[512 + tid];
}

extern "C" void kernel_launch(void* const* d_in, const int* in_sizes, int n_in,
                              void* d_out, int out_size, void* d_ws, size_t ws_size,
                              hipStream_t stream) {
  const float* x = (const float*)d_in[0];
  const int* mask = (const int*)d_in[1];
  const float* Wh = (const float*)d_in[2];
  const float* bh = (const float*)d_in[3];
  const float* Wo = (const float*)d_in[4];
  const float* bo = (const float*)d_in[5];
  const float* gamma = (const float*)d_in[6];
  const float* beta = (const float*)d_in[7];
  float* out = (float*)d_out;

  // ---- workspace: phase-aliased regions, total ~215.5 MB ----
  const size_t nX = (size_t)B_ * S_ * E_;        // 3,145,728
  const size_t nP = (size_t)B_ * H_ * S_ * E_;   // 37,748,736
  const size_t nSc = (size_t)B_ * H_ * S_ * S_;  // 25,165,824
  char* base = (char*)d_ws;
  // R_A: p, later cat (p dead after pT transpose + GEMM2)
  __hip_bfloat16* p = (__hip_bfloat16*)base;
  __hip_bfloat16* cat = p;
  char* RB = base + nP * 2;  // 75,497,472 B
  // R_B: pT, later y partials (pT dead after GEMM3); 6 x 12.58MB fp32 = 75.5MB exact
  __hip_bfloat16* pT = (__hip_bfloat16*)RB;
  float* ypart = (float*)RB;
  char* RC = RB + nP * 2;
  // R_C: xb + WhT early (dead after GEMM1), then scores/attn bf16 (in-place softmax)
  __hip_bfloat16* xb = (__hip_bfloat16*)RC;
  __hip_bfloat16* WhT = (__hip_bfloat16*)(RC + nX * 2);
  __hip_bfloat16* scores = (__hip_bfloat16*)RC;
  char* RD = RC + nSc * 2;
  // R_D: WoT (live until GEMM4)
  __hip_bfloat16* WoT = (__hip_bfloat16*)RD;

  dim3 t256(256);
  dim3 tT(32, 8);
  const float inv_sqrtE = 1.0f / sqrtf((float)E_);

  // 1. x -> bf16
  cvt_kernel<<<dim3(nX / 256), t256, 0, stream>>>(x, xb, (int)nX);
  // 2. WhT[h][o][e] = Wh[h][e][o]
  transpose_kernel<float><<<dim3(24, 24, 12), tT, 0, stream>>>(Wh, (long)E_ * E_, WhT,
                                                               (long)E_ * E_, E_, E_);
  // 3. WoT[o][k] = Wo[k][o]  (k over H*E)
  transpose_kernel<float><<<dim3(24, 288, 1), tT, 0, stream>>>(Wo, 0, WoT, 0, HE_, E_);
  // 4. p[b,h,s,o] = x[b,s,:]·Wh[h,:,o] + bh[h,o]   (bf16 out)
  //    grid 6x4x96 = 2304 blocks (%8==0)
  gemm_bt<true, true><<<dim3(6 * 4 * 96), t256, 0, stream>>>(
      xb, (long)S_ * E_, 0, E_, WhT, 0, (long)E_ * E_, E_, p, (long)H_ * S_ * E_,
      (long)S_ * E_, E_, bh, E_, H_, E_, 1.0f, 6, 4);
  // 5. pT[b,h,e,s] = p[b,h,s,e]
  transpose_kernel<__hip_bfloat16><<<dim3(24, 16, B_ * H_), tT, 0, stream>>>(
      p, (long)S_ * E_, pT, (long)S_ * E_, S_, E_);
  // 6. scores = (p · p^T) / sqrt(E)   (bf16 out, overwrites dead xb/WhT)
  //    grid 4x4x96 = 1536 blocks
  gemm_bt<true, false><<<dim3(4 * 4 * 96), t256, 0, stream>>>(
      p, (long)H_ * S_ * E_, (long)S_ * E_, E_, p, (long)H_ * S_ * E_, (long)S_ * E_, E_,
      scores, (long)H_ * S_ * S_, (long)S_ * S_, S_, nullptr, 0, H_, E_, inv_sqrtE, 4, 4);
  // 7. masked softmax in-place -> attn (bf16)
  softmax_kernel<<<dim3(S_, H_, B_), t256, 0, stream>>>(scores, mask);
  // 8. o = attn · p  written straight into cat[b,s,h*E+e]  (bf16, overwrites dead p)
  //    grid 6x4x96 = 2304 blocks
  gemm_bt<true, false><<<dim3(6 * 4 * 96), t256, 0, stream>>>(
      scores, (long)H_ * S_ * S_, (long)S_ * S_, S_, pT, (long)H_ * E_ * S_, (long)E_ * S_,
      S_, cat, (long)S_ * HE_, (long)E_, HE_, nullptr, 0, H_, S_, 1.0f, 6, 4);
  // 9. split-K: ypart[c] = cat[:, c*1536:+1536] · WoT[:, c*1536:+1536]^T  (fp32)
  //    grid 6x32x6 = 1152 blocks
  gemm_bt<false, false><<<dim3(6 * 32 * KSPLIT), t256, 0, stream>>>(
      cat, 0, KCHUNK, HE_, WoT, 0, KCHUNK, HE_, ypart, 0, (long)B_ * S_ * E_, E_,
      nullptr, 0, KSPLIT, KCHUNK, 1.0f, 6, 32);
  // 10. reduce partials + bias + LayerNorm -> out
  ln_kernel<<<dim3(B_ * S_), t256, 0, stream>>>(ypart, bo, gamma, beta, out);
}

// Round 5
// 353.876 us; speedup vs baseline: 1.6494x; 1.3063x over previous
//
#include <hip/hip_runtime.h>
#include <hip/hip_bf16.h>
#include <math.h>

#define B_ 8
#define S_ 512
#define E_ 768
#define H_ 12
#define HE_ (H_ * E_)
#define KSPLIT 6
#define KCHUNK (HE_ / KSPLIT)  // 1536

typedef __attribute__((ext_vector_type(8))) short bf16x8;
typedef __attribute__((ext_vector_type(4))) float f32x4;

__device__ inline void gload_lds16(const void* g, void* l) {
  __builtin_amdgcn_global_load_lds(
      (const __attribute__((address_space(1))) unsigned int*)g,
      (__attribute__((address_space(3))) unsigned int*)l, 16, 0, 0);
}

__device__ inline float tof(float v) { return v; }
__device__ inline float tof(__hip_bfloat16 v) { return __bfloat162float(v); }

// ---------- f32 -> bf16 convert ----------
__global__ __launch_bounds__(256) void cvt_kernel(const float* __restrict__ in,
                                                  __hip_bfloat16* __restrict__ out, int n) {
  int i = blockIdx.x * 256 + threadIdx.x;
  if (i < n) out[i] = __float2bfloat16(in[i]);
}

// ---------- transpose [R][C] -> bf16 [C][R], batched over z ----------
template <typename T>
__global__ __launch_bounds__(256) void transpose_kernel(const T* __restrict__ in, long inz,
                                                        __hip_bfloat16* __restrict__ out,
                                                        long outz, int R, int C) {
  __shared__ float t[32][33];
  in += (long)blockIdx.z * inz;
  out += (long)blockIdx.z * outz;
  int bc = blockIdx.x * 32, br = blockIdx.y * 32;
  int tx = threadIdx.x, ty = threadIdx.y;  // block (32,8)
#pragma unroll
  for (int i = ty; i < 32; i += 8) t[i][tx] = tof(in[(long)(br + i) * C + (bc + tx)]);
  __syncthreads();
#pragma unroll
  for (int i = ty; i < 32; i += 8)
    out[(long)(bc + i) * R + (br + tx)] = __float2bfloat16(t[tx][i]);
}

// ---------- MFMA GEMM: C[M,N] = A[M,K] * (BT[N,K])^T, bf16 in, fp32 accum ----------
// 1D grid with XCD-chunked swizzle (T1): requires gridDim.x % 8 == 0.
// LDS layout: XOR-swizzled at 8-elem (16B) chunk granularity:
//   LDS elem row*64 + cc*8 holds global col chunk (cc ^ (row&7)).
// Staging keeps LDS dest linear (global_load_lds requirement) and permutes the
// SOURCE column; reads apply the same XOR. 2-way max bank aliasing (free).
template <bool OUT_BF16, bool ADD_BIAS>
__global__ __launch_bounds__(256) void gemm_bt(
    const __hip_bfloat16* __restrict__ A, long As1, long As2, int lda,
    const __hip_bfloat16* __restrict__ BT, long Bs1, long Bs2, int ldb,
    void* __restrict__ Cv, long Cs1, long Cs2, int ldc,
    const float* __restrict__ bias, long biasS2, int zmod, int K, float scale,
    int nx, int ny) {
  constexpr int BM = 128, BN = 128, BK = 64;
  __shared__ __align__(16) __hip_bfloat16 sA[BM * BK];
  __shared__ __align__(16) __hip_bfloat16 sB[BN * BK];
  // T1: XCD-chunked bijective remap (nwg % 8 == 0 guaranteed by launches).
  const int nwg = gridDim.x;
  const int cpx = nwg >> 3;
  const int id = blockIdx.x;
  const int w = (id & 7) * cpx + (id >> 3);
  const int bz = w / (nx * ny);
  const int rem = w - bz * nx * ny;
  const int by = rem / nx;
  const int bx = rem - by * nx;

  const int tid = threadIdx.x;
  const int wave = tid >> 6, lane = tid & 63;
  const int r16 = lane & 15, g = lane >> 4;  // fragment row/col within 16, k-group
  const int zb = bz / zmod, zh = bz % zmod;
  A += (long)zb * As1 + (long)zh * As2;
  BT += (long)zb * Bs1 + (long)zh * Bs2;
  const int bm = by * BM, bn = bx * BN;
  const int wm = (wave >> 1) * 64, wn = (wave & 1) * 64;
  f32x4 acc[4][4] = {};
  const int e0 = tid * 8;  // staging: 8 bf16 (16B) per thread per pass

  for (int k0 = 0; k0 < K; k0 += BK) {
#pragma unroll
    for (int p = 0; p < 4; ++p) {  // 4 passes x 256 thr x 8 elems = 128x64 tile
      int ee = p * 2048 + e0;
      int row = ee >> 6;
      int col = (ee & 63) ^ ((row & 7) << 3);  // source-side inverse swizzle
      gload_lds16(A + (long)(bm + row) * lda + (k0 + col), (char*)sA + ee * 2);
      gload_lds16(BT + (long)(bn + row) * ldb + (k0 + col), (char*)sB + ee * 2);
    }
    __syncthreads();  // drains vmcnt for global_load_lds
#pragma unroll
    for (int kk = 0; kk < BK; kk += 32) {
      bf16x8 af[4], bfr[4];
#pragma unroll
      for (int i = 0; i < 4; ++i) {
        int row = wm + i * 16 + r16;
        int c = (kk + g * 8) ^ ((row & 7) << 3);  // read-side swizzle
        af[i] = *(const bf16x8*)(const void*)(sA + row * BK + c);
      }
#pragma unroll
      for (int j = 0; j < 4; ++j) {
        int row = wn + j * 16 + r16;
        int c = (kk + g * 8) ^ ((row & 7) << 3);
        bfr[j] = *(const bf16x8*)(const void*)(sB + row * BK + c);
      }
#pragma unroll
      for (int i = 0; i < 4; ++i)
#pragma unroll
        for (int j = 0; j < 4; ++j)
          acc[i][j] = __builtin_amdgcn_mfma_f32_16x16x32_bf16(af[i], bfr[j], acc[i][j], 0, 0, 0);
    }
    __syncthreads();
  }

  float* Cf = (float*)Cv;
  __hip_bfloat16* Cb = (__hip_bfloat16*)Cv;
  const long cbase = (long)zb * Cs1 + (long)zh * Cs2;
#pragma unroll
  for (int i = 0; i < 4; ++i) {
    int row0 = bm + wm + i * 16 + g * 4;
#pragma unroll
    for (int j = 0; j < 4; ++j) {
      int col = bn + wn + j * 16 + r16;
      float bv = ADD_BIAS ? bias[(long)zh * biasS2 + col] : 0.0f;
#pragma unroll
      for (int r = 0; r < 4; ++r) {
        float v = acc[i][j][r] * scale + bv;
        long off = cbase + (long)(row0 + r) * ldc + col;
        if (OUT_BF16)
          Cb[off] = __float2bfloat16(v);
        else
          Cf[off] = v;
      }
    }
  }
}

// ---------- masked softmax over rows of 512, bf16 in -> bf16 out, IN-PLACE ----------
__global__ __launch_bounds__(256) void softmax_kernel(__hip_bfloat16* __restrict__ scores,
                                                      const int* __restrict__ mask) {
  const int q = blockIdx.x, h = blockIdx.y, b = blockIdx.z;
  const int tid = threadIdx.x;
  const long base = (((long)b * H_ + h) * S_ + q) * S_;
  const int* mrow = mask + (long)b * S_;
  float v0 = __bfloat162float(scores[base + tid]);
  float v1 = __bfloat162float(scores[base + 256 + tid]);
  if (mrow[tid] == 1) v0 = -INFINITY;
  if (mrow[256 + tid] == 1) v1 = -INFINITY;
  float m = fmaxf(v0, v1);
#pragma unroll
  for (int o = 32; o; o >>= 1) m = fmaxf(m, __shfl_xor(m, o));
  __shared__ float red[8];
  const int wave = tid >> 6, lane = tid & 63;
  if (lane == 0) red[wave] = m;
  __syncthreads();
  m = fmaxf(fmaxf(red[0], red[1]), fmaxf(red[2], red[3]));
  float e0 = expf(v0 - m), e1 = expf(v1 - m);
  float s = e0 + e1;
#pragma unroll
  for (int o = 32; o; o >>= 1) s += __shfl_xor(s, o);
  if (lane == 0) red[4 + wave] = s;
  __syncthreads();
  s = red[4] + red[5] + red[6] + red[7];
  float inv = 1.0f / s;
  scores[base + tid] = __float2bfloat16(e0 * inv);
  scores[base + 256 + tid] = __float2bfloat16(e1 * inv);
}

// ---------- reduce KSPLIT bf16 partials + bias + LayerNorm over E=768 ----------
__global__ __launch_bounds__(256) void ln_kernel(const __hip_bfloat16* __restrict__ yp,
                                                 const float* __restrict__ bo,
                                                 const float* __restrict__ gamma,
                                                 const float* __restrict__ beta,
                                                 float* __restrict__ out) {
  const long nY = (long)B_ * S_ * E_;
  const long base = (long)blockIdx.x * E_;
  const int tid = threadIdx.x;
  float a = bo[tid], b = bo[256 + tid], c = bo[512 + tid];
#pragma unroll
  for (int k = 0; k < KSPLIT; ++k) {
    const __hip_bfloat16* y = yp + k * nY + base;
    a += __bfloat162float(y[tid]);
    b += __bfloat162float(y[256 + tid]);
    c += __bfloat162float(y[512 + tid]);
  }
  float s = a + b + c;
  float ss = a * a + b * b + c * c;
#pragma unroll
  for (int o = 32; o; o >>= 1) {
    s += __shfl_xor(s, o);
    ss += __shfl_xor(ss, o);
  }
  __shared__ float r1[4], r2[4];
  const int wave = tid >> 6, lane = tid & 63;
  if (lane == 0) { r1[wave] = s; r2[wave] = ss; }
  __syncthreads();
  s = r1[0] + r1[1] + r1[2] + r1[3];
  ss = r2[0] + r2[1] + r2[2] + r2[3];
  const float mu = s * (1.0f / E_);
  const float var = ss * (1.0f / E_) - mu * mu;
  const float rstd = rsqrtf(var + 1e-5f);
  out[base + tid] = (a - mu) * rstd * gamma[tid] + beta[tid];
  out[base + 256 + tid] = (b - mu) * rstd * gamma[256 + tid] + beta[256 + tid];
  out[base + 512 + tid] = (c - mu) * rstd * gamma[512 + tid] + beta[512 + tid];
}

extern "C" void kernel_launch(void* const* d_in, const int* in_sizes, int n_in,
                              void* d_out, int out_size, void* d_ws, size_t ws_size,
                              hipStream_t stream) {
  const float* x = (const float*)d_in[0];
  const int* mask = (const int*)d_in[1];
  const float* Wh = (const float*)d_in[2];
  const float* bh = (const float*)d_in[3];
  const float* Wo = (const float*)d_in[4];
  const float* bo = (const float*)d_in[5];
  const float* gamma = (const float*)d_in[6];
  const float* beta = (const float*)d_in[7];
  float* out = (float*)d_out;

  // ---- workspace: phase-aliased regions, total ~215.5 MB ----
  const size_t nX = (size_t)B_ * S_ * E_;        // 3,145,728
  const size_t nP = (size_t)B_ * H_ * S_ * E_;   // 37,748,736
  const size_t nSc = (size_t)B_ * H_ * S_ * S_;  // 25,165,824
  char* base = (char*)d_ws;
  // R_A: p, later cat (p dead after pT transpose + GEMM2)
  __hip_bfloat16* p = (__hip_bfloat16*)base;
  __hip_bfloat16* cat = p;
  char* RB = base + nP * 2;  // 75,497,472 B
  // R_B: pT, later y partials (pT dead after GEMM3); 6 x 6.3MB bf16 = 37.7MB
  __hip_bfloat16* pT = (__hip_bfloat16*)RB;
  __hip_bfloat16* ypart = (__hip_bfloat16*)RB;
  char* RC = RB + nP * 2;
  // R_C: xb + WhT early (dead after GEMM1), then scores/attn bf16 (in-place softmax)
  __hip_bfloat16* xb = (__hip_bfloat16*)RC;
  __hip_bfloat16* WhT = (__hip_bfloat16*)(RC + nX * 2);
  __hip_bfloat16* scores = (__hip_bfloat16*)RC;
  char* RD = RC + nSc * 2;
  // R_D: WoT (live until GEMM4)
  __hip_bfloat16* WoT = (__hip_bfloat16*)RD;

  dim3 t256(256);
  dim3 tT(32, 8);
  const float inv_sqrtE = 1.0f / sqrtf((float)E_);

  // 1. x -> bf16
  cvt_kernel<<<dim3(nX / 256), t256, 0, stream>>>(x, xb, (int)nX);
  // 2. WhT[h][o][e] = Wh[h][e][o]
  transpose_kernel<float><<<dim3(24, 24, 12), tT, 0, stream>>>(Wh, (long)E_ * E_, WhT,
                                                               (long)E_ * E_, E_, E_);
  // 3. WoT[o][k] = Wo[k][o]  (k over H*E)
  transpose_kernel<float><<<dim3(24, 288, 1), tT, 0, stream>>>(Wo, 0, WoT, 0, HE_, E_);
  // 4. p[b,h,s,o] = x[b,s,:]·Wh[h,:,o] + bh[h,o]   (bf16 out)
  //    grid 6x4x96 = 2304 blocks (%8==0)
  gemm_bt<true, true><<<dim3(6 * 4 * 96), t256, 0, stream>>>(
      xb, (long)S_ * E_, 0, E_, WhT, 0, (long)E_ * E_, E_, p, (long)H_ * S_ * E_,
      (long)S_ * E_, E_, bh, E_, H_, E_, 1.0f, 6, 4);
  // 5. pT[b,h,e,s] = p[b,h,s,e]
  transpose_kernel<__hip_bfloat16><<<dim3(24, 16, B_ * H_), tT, 0, stream>>>(
      p, (long)S_ * E_, pT, (long)S_ * E_, S_, E_);
  // 6. scores = (p · p^T) / sqrt(E)   (bf16 out, overwrites dead xb/WhT)
  //    grid 4x4x96 = 1536 blocks
  gemm_bt<true, false><<<dim3(4 * 4 * 96), t256, 0, stream>>>(
      p, (long)H_ * S_ * E_, (long)S_ * E_, E_, p, (long)H_ * S_ * E_, (long)S_ * E_, E_,
      scores, (long)H_ * S_ * S_, (long)S_ * S_, S_, nullptr, 0, H_, E_, inv_sqrtE, 4, 4);
  // 7. masked softmax in-place -> attn (bf16)
  softmax_kernel<<<dim3(S_, H_, B_), t256, 0, stream>>>(scores, mask);
  // 8. o = attn · p  written straight into cat[b,s,h*E+e]  (bf16, overwrites dead p)
  //    grid 6x4x96 = 2304 blocks
  gemm_bt<true, false><<<dim3(6 * 4 * 96), t256, 0, stream>>>(
      scores, (long)H_ * S_ * S_, (long)S_ * S_, S_, pT, (long)H_ * E_ * S_, (long)E_ * S_,
      S_, cat, (long)S_ * HE_, (long)E_, HE_, nullptr, 0, H_, S_, 1.0f, 6, 4);
  // 9. split-K: ypart[c] = cat[:, c*1536:+1536] · WoT[:, c*1536:+1536]^T  (bf16 partials)
  //    grid 6x32x6 = 1152 blocks
  gemm_bt<true, false><<<dim3(6 * 32 * KSPLIT), t256, 0, stream>>>(
      cat, 0, KCHUNK, HE_, WoT, 0, KCHUNK, HE_, ypart, 0, (long)B_ * S_ * E_, E_,
      nullptr, 0, KSPLIT, KCHUNK, 1.0f, 6, 32);
  // 10. reduce partials + bias + LayerNorm -> out
  ln_kernel<<<dim3(B_ * S_), t256, 0, stream>>>(ypart, bo, gamma, beta, out);
}